// Round 9
// baseline (159.597 us; speedup 1.0000x reference)
//
#include <hip/hip_runtime.h>

// TriAffine: S[b,x,y,z] = sum_{i,k,j} xb[b,x,i] z[b,z,k] W[i,k,j] yb[b,y,j]
// B=2, L=256, N_IN=128. Output [2,256,256,256] f32 (134 MB).
//
// === MEASUREMENT ROUND ===
// Identical kernels to r8; stage2 launched 3x (idempotent, deterministic).
// dur_us = FE + 3*S2  ->  S2 = (dur - 84.7)/2. Pins the per-kernel split
// that the fill-dominated rocprof top-5 hides.
//
//  prep   : x,y,z f32 -> bf16
//  stage1f: fused W-stage (LDS) + flat GEMM A2[bx][n'], n' = k*136+j
//  stage2 : per (b,x): A2->LDS (float4); phaseA P'[k,y]; P'->LDS[y][132];
//           phaseB wave = 64z x 128y, z frags in regs.

typedef __bf16 bf16x8 __attribute__((ext_vector_type(8)));
typedef short short4_t __attribute__((ext_vector_type(4)));
typedef float f32x4 __attribute__((ext_vector_type(4)));
typedef unsigned short ushort4_t __attribute__((ext_vector_type(4)));

#define LL 256
#define NI 128
#define NFLATP 17408           // 128 * 136 (padded (k,j) axis)
#define KJ_STRIDE 136          // j-stride within A2 row / LDS
#define P_STRIDE 132           // P' LDS k-stride (264B)

__device__ __forceinline__ unsigned short f2bf(float f) {
    unsigned u = __builtin_bit_cast(unsigned, f);
    u += 0x7FFFu + ((u >> 16) & 1u);   // RNE
    return (unsigned short)(u >> 16);
}
__device__ __forceinline__ float bf2f(unsigned short h) {
    return __builtin_bit_cast(float, (unsigned)h << 16);
}

// ---------------- prep: x,y,z f32 -> bf16 (3 x 65536 elems) ----------------
__global__ __launch_bounds__(256) void prep_kernel(const float* __restrict__ x,
                                                   const float* __restrict__ y,
                                                   const float* __restrict__ z,
                                                   unsigned short* __restrict__ xyz) {
    int t = blockIdx.x * 256 + threadIdx.x;      // 0..49151
    int base = t * 4;
    int which = base >> 16;
    int local = base & 65535;
    const float* s = (which == 0) ? x : (which == 1) ? y : z;
    float4 v = *(const float4*)(s + local);
    ushort4_t o;
    o[0] = f2bf(v.x); o[1] = f2bf(v.y); o[2] = f2bf(v.z); o[3] = f2bf(v.w);
    *(ushort4_t*)(xyz + base) = o;
}

// ---------------- stage1f: fused W-stage + flat GEMM A2[bx][n'] ----------------
__global__ __launch_bounds__(512) void stage1f_kernel(const float* __restrict__ W,
                                                      const unsigned short* __restrict__ xbf,
                                                      unsigned short* __restrict__ A2g) {
    const int bxg = blockIdx.x;            // 0..1
    const int nb  = blockIdx.y;            // 0..135
    const int tid = threadIdx.x;

    __shared__ unsigned short T[128 * KJ_STRIDE];   // 34816 B: [n_local][i]

    {   // stage: T[nl][i] = bf16(W[i][k(n')*129 + j(n')]), pad j -> 0
        const int nl = tid & 127;          // local n-row
        const int ig = tid >> 7;           // 0..3: i stride-4 phase
        const int np = nb * 128 + nl;      // padded flat index
        const int k  = np / KJ_STRIDE;
        const int j  = np - k * KJ_STRIDE; // 0..135
        const bool jok = (j <= 128);
        const float* Wkj = W + (size_t)k * 129 + j;
#pragma unroll 4
        for (int r = 0; r < 33; ++r) {
            int i = ig + r * 4;
            if (i <= 128) {
                float v = jok ? Wkj[(size_t)i * 16512] : 0.f;
                T[nl * KJ_STRIDE + i] = f2bf(v);
            }
        }
    }
    __syncthreads();

    const int wv = tid >> 6, lane = tid & 63;
    const int l15 = lane & 15, h = lane >> 4;
    const int nsub = wv & 3;               // n-quarter within tile
    const int bxh  = wv >> 2;              // bx-half within block
    const int nloc = nsub * 32;
    const int nglob = nb * 128 + nloc;
    const int bx0 = bxg * 256 + bxh * 128;

    bf16x8 af[2][4];
#pragma unroll
    for (int nt = 0; nt < 2; ++nt)
#pragma unroll
        for (int is = 0; is < 4; ++is)
            af[nt][is] = *(const bf16x8*)&T[(nloc + nt * 16 + l15) * KJ_STRIDE + is * 32 + 8 * h];

    f32x4 acc[2][8];
#pragma unroll
    for (int nt = 0; nt < 2; ++nt) {
        f32x4 binit;
#pragma unroll
        for (int r = 0; r < 4; ++r)
            binit[r] = bf2f(T[(nloc + nt * 16 + 4 * h + r) * KJ_STRIDE + 128]);   // bias i=128
#pragma unroll
        for (int ct = 0; ct < 8; ++ct) acc[nt][ct] = binit;
    }

#pragma unroll
    for (int is = 0; is < 4; ++is)
#pragma unroll
        for (int ct = 0; ct < 8; ++ct) {
            bf16x8 xf = *(const bf16x8*)(xbf + (bx0 + ct * 16 + l15) * NI + is * 32 + 8 * h);
            acc[0][ct] = __builtin_amdgcn_mfma_f32_16x16x32_bf16(af[0][is], xf, acc[0][ct], 0, 0, 0);
            acc[1][ct] = __builtin_amdgcn_mfma_f32_16x16x32_bf16(af[1][is], xf, acc[1][ct], 0, 0, 0);
        }

#pragma unroll
    for (int nt = 0; nt < 2; ++nt)
#pragma unroll
        for (int ct = 0; ct < 8; ++ct) {
            ushort4_t o;
#pragma unroll
            for (int r = 0; r < 4; ++r) o[r] = f2bf(acc[nt][ct][r]);
            *(ushort4_t*)(A2g + (size_t)(bx0 + ct * 16 + l15) * NFLATP + nglob + nt * 16 + 4 * h) = o;
        }
}

// ---------------- stage2: per (b,x) block -> S[y,z] 256x256 ----------------
__global__ __launch_bounds__(512, 4) void stage2_kernel(const unsigned short* __restrict__ ybf,
                                                        const unsigned short* __restrict__ zbf,
                                                        const unsigned short* __restrict__ A2g,
                                                        float* __restrict__ out) {
    const int bx  = blockIdx.x;            // b*256 + x
    const int b   = bx >> 8;
    const int tid = threadIdx.x;
    const int wv = tid >> 6, lane = tid & 63;
    const int l15 = lane & 15, h = lane >> 4;

    __shared__ __align__(16) unsigned short SH[LL * P_STRIDE];   // 67584 B

    {   // pure vector staging: A2 row layout == LDS layout
        const float4* src = (const float4*)(A2g + (size_t)bx * NFLATP);
        float4* dst = (float4*)SH;
        for (int t = tid; t < NFLATP / 8; t += 512) dst[t] = src[t];
    }
    __syncthreads();

    const unsigned short* yb = ybf + b * LL * NI;
    const unsigned short* zb = zbf + b * LL * NI;
    const int y0 = wv * 32;                // wave owns 32 of 256 y in phase A

    // ---- Phase A: P'[k,y] = sum_j A2[k,j]*y[y,j] + A2[k,128] ----
    f32x4 accP[8][2];                      // [k-tile][y-tile]; lane: y=l15(col), k=4h+r(row)
#pragma unroll
    for (int kt = 0; kt < 8; ++kt)
#pragma unroll
        for (int r = 0; r < 4; ++r) {
            float bias = bf2f(SH[(kt * 16 + 4 * h + r) * KJ_STRIDE + 128]);
            accP[kt][0][r] = bias; accP[kt][1][r] = bias;
        }
#pragma unroll
    for (int js = 0; js < 4; ++js) {
        bf16x8 yf[2];
#pragma unroll
        for (int yt = 0; yt < 2; ++yt)
            yf[yt] = *(const bf16x8*)(yb + (y0 + yt * 16 + l15) * NI + js * 32 + 8 * h);
#pragma unroll
        for (int kt = 0; kt < 8; ++kt) {
            bf16x8 af = *(const bf16x8*)&SH[(kt * 16 + l15) * KJ_STRIDE + js * 32 + 8 * h];
            accP[kt][0] = __builtin_amdgcn_mfma_f32_16x16x32_bf16(af, yf[0], accP[kt][0], 0, 0, 0);
            accP[kt][1] = __builtin_amdgcn_mfma_f32_16x16x32_bf16(af, yf[1], accP[kt][1], 0, 0, 0);
        }
    }
    __syncthreads();   // all waves done reading A2 region

    // ---- P' -> LDS [y][P_STRIDE] bf16 ----
#pragma unroll
    for (int kt = 0; kt < 8; ++kt)
#pragma unroll
        for (int yt = 0; yt < 2; ++yt) {
            unsigned lo = (unsigned)f2bf(accP[kt][yt][0]) | ((unsigned)f2bf(accP[kt][yt][1]) << 16);
            unsigned hi = (unsigned)f2bf(accP[kt][yt][2]) | ((unsigned)f2bf(accP[kt][yt][3]) << 16);
            uint2 v; v.x = lo; v.y = hi;
            *(uint2*)&SH[(y0 + yt * 16 + l15) * P_STRIDE + kt * 16 + 4 * h] = v;
        }

    // z fragments: wave owns 64 z-rows, loaded once (overlaps ds_writes above)
    const int zg = wv & 3, yh = wv >> 2;
    const int z0 = zg * 64;
    short4_t zf[4][8];
#pragma unroll
    for (int zt = 0; zt < 4; ++zt)
#pragma unroll
        for (int kt = 0; kt < 8; ++kt)
            zf[zt][kt] = *(const short4_t*)(zb + (z0 + zt * 16 + l15) * NI + kt * 16 + 4 * h);

    __syncthreads();   // P' visible

    // ---- Phase B: S[y,z] = sum_k z[z,k]*P'[k,y]; wave: 64 z x 128 y ----
    float* outb = out + (size_t)bx * (LL * LL);
#pragma unroll 1
    for (int yti = 0; yti < 8; ++yti) {
        const int yy = yh * 128 + yti * 16 + l15;    // this lane's y (col)
        f32x4 acc2[4];
#pragma unroll
        for (int zt = 0; zt < 4; ++zt) { acc2[zt][0] = 0.f; acc2[zt][1] = 0.f; acc2[zt][2] = 0.f; acc2[zt][3] = 0.f; }
#pragma unroll
        for (int kt = 0; kt < 8; ++kt) {
            short4_t pB = *(const short4_t*)&SH[yy * P_STRIDE + kt * 16 + 4 * h];
#pragma unroll
            for (int zt = 0; zt < 4; ++zt)
                acc2[zt] = __builtin_amdgcn_mfma_f32_16x16x16bf16_1k(zf[zt][kt], pB, acc2[zt], 0, 0, 0);
        }
#pragma unroll
        for (int zt = 0; zt < 4; ++zt)
            *(f32x4*)(outb + (size_t)yy * LL + z0 + zt * 16 + 4 * h) = acc2[zt];
    }
}

extern "C" void kernel_launch(void* const* d_in, const int* in_sizes, int n_in,
                              void* d_out, int out_size, void* d_ws, size_t ws_size,
                              hipStream_t stream) {
    const float* x = (const float*)d_in[0];
    const float* y = (const float*)d_in[1];
    const float* z = (const float*)d_in[2];
    const float* W = (const float*)d_in[3];   // [129][128][129][1] = [129][16512]
    float* out = (float*)d_out;

    unsigned short* xbf = (unsigned short*)d_ws;             // 65536
    unsigned short* ybf = xbf + 65536;                       // 65536
    unsigned short* zbf = ybf + 65536;                       // 65536
    unsigned short* A2g = zbf + 65536;                       // 512*17408 (~17.8 MB)

    prep_kernel<<<192, 256, 0, stream>>>(x, y, z, xbf);
    stage1f_kernel<<<dim3(2, 136), 512, 0, stream>>>(W, xbf, A2g);
    // stage2 x3 (idempotent): dur_us = FE + 3*S2 -> isolates S2 vs r8's FE + S2.
    stage2_kernel<<<512, 512, 0, stream>>>(ybf, zbf, A2g, out);
    stage2_kernel<<<512, 512, 0, stream>>>(ybf, zbf, A2g, out);
    stage2_kernel<<<512, 512, 0, stream>>>(ybf, zbf, A2g, out);
}

// Round 10
// 67.449 us; speedup vs baseline: 2.3662x; 2.3662x over previous
//
#include <hip/hip_runtime.h>

// TriAffine: S[b,x,y,z] = sum_{i,k,j} xb[b,x,i] z[b,z,k] W[i,k,j] yb[b,y,j]
// B=2, L=256, N_IN=128. Output [2,256,256,256] f32 (134 MB).
//
// r9 measurement: S2 = 37.4us, FE = 47.3us (8x over traffic floor). This
// round collapses the FE to ONE launch:
//  stage1f: blocks 0..271: x f32 -> bf16 into LDS (inline, kills prep->xbf
//           round-trip) + W tile -> LDS via 33-reg full-unroll batch loads
//           (one latency exposure) + flat GEMM A2[bx][n'] (n' = k*136+j).
//           blocks 272..335: y,z f32 -> bf16 (consumed only by stage2).
//  stage2 : UNCHANGED from r8/r9 baseline (37.4us known) -> dur - 37.4 = FE'.

typedef __bf16 bf16x8 __attribute__((ext_vector_type(8)));
typedef short short4_t __attribute__((ext_vector_type(4)));
typedef float f32x4 __attribute__((ext_vector_type(4)));
typedef unsigned short ushort4_t __attribute__((ext_vector_type(4)));

#define LL 256
#define NI 128
#define NFLATP 17408           // 128 * 136 (padded (k,j) axis)
#define KJ_STRIDE 136          // j-stride within A2 row / LDS
#define XB_STRIDE 132          // x LDS i-stride (264B, conflict-free b128)
#define P_STRIDE 132           // P' LDS k-stride (264B)

__device__ __forceinline__ unsigned short f2bf(float f) {
    unsigned u = __builtin_bit_cast(unsigned, f);
    u += 0x7FFFu + ((u >> 16) & 1u);   // RNE
    return (unsigned short)(u >> 16);
}
__device__ __forceinline__ float bf2f(unsigned short h) {
    return __builtin_bit_cast(float, (unsigned)h << 16);
}

// ---------------- stage1f: fused {x-cvt, W-stage, GEMM} + yz-prep ----------------
// blocks 0..271: (bxg = blk&1, nb = blk>>1); 512 thr (8 waves).
// blocks 272..335: y,z f32 -> bf16 (64 blocks x 512 thr x 4 elems = 131072).
__global__ __launch_bounds__(512) void stage1f_kernel(const float* __restrict__ W,
                                                      const float* __restrict__ x,
                                                      const float* __restrict__ y,
                                                      const float* __restrict__ z,
                                                      unsigned short* __restrict__ yzbf,
                                                      unsigned short* __restrict__ A2g) {
    const int blk = blockIdx.x, tid = threadIdx.x;

    if (blk >= 272) {           // ---- yz prep ----
        int t = (blk - 272) * 512 + tid;   // 0..32767
        int base = t * 4;                  // 0..131068
        int which = base >> 16;            // 0: y, 1: z
        int local = base & 65535;
        const float* s = which ? z : y;
        float4 v = *(const float4*)(s + local);
        ushort4_t o;
        o[0] = f2bf(v.x); o[1] = f2bf(v.y); o[2] = f2bf(v.z); o[3] = f2bf(v.w);
        *(ushort4_t*)(yzbf + base) = o;
        return;
    }

    const int bxg = blk & 1;               // 0..1 (bx half)
    const int nb  = blk >> 1;              // 0..135

    __shared__ unsigned short T[128 * KJ_STRIDE];    // 34816 B: [n_local][i]
    __shared__ unsigned short XB[256 * XB_STRIDE];   // 67584 B: [bx_local][i]

    {   // ---- W stage: T[nl][i] = bf16(W[i][k*129+j]); all loads batch-issued ----
        const int nl = tid & 127;          // local n-row
        const int ig = tid >> 7;           // 0..3: i stride-4 phase (wave-uniform)
        const int np = nb * 128 + nl;
        const int k  = np / KJ_STRIDE;
        const int j  = np - k * KJ_STRIDE; // 0..135
        const bool jok = (j <= 128);
        const float* Wkj = W + (size_t)k * 129 + j;
        float wreg[33];
#pragma unroll
        for (int r = 0; r < 33; ++r) {
            int i = ig + r * 4;
            wreg[r] = (i <= 128 && jok) ? Wkj[(size_t)i * 16512] : 0.f;
        }
#pragma unroll
        for (int r = 0; r < 33; ++r) {
            int i = ig + r * 4;
            if (i <= 128) T[nl * KJ_STRIDE + i] = f2bf(wreg[r]);
        }
    }

    {   // ---- x stage: XB[bx_local][i] = bf16(x[bxg*256 + bx_local][i]) ----
        const float* xsrc = x + (size_t)bxg * 256 * NI;   // 32768 floats
#pragma unroll 4
        for (int c = 0; c < 16; ++c) {
            int idx = c * 512 + tid;       // float4 index 0..8191
            float4 v = *(const float4*)(xsrc + (size_t)idx * 4);
            int fid = idx * 4;
            int row = fid >> 7, col = fid & 127;
            ushort4_t o;
            o[0] = f2bf(v.x); o[1] = f2bf(v.y); o[2] = f2bf(v.z); o[3] = f2bf(v.w);
            *(ushort4_t*)&XB[row * XB_STRIDE + col] = o;
        }
    }
    __syncthreads();

    const int wv = tid >> 6, lane = tid & 63;
    const int l15 = lane & 15, h = lane >> 4;
    const int nsub = wv & 3;               // n-quarter within tile
    const int bxh  = wv >> 2;              // bx-half within block
    const int nloc = nsub * 32;
    const int nglob = nb * 128 + nloc;
    const int bx0 = bxg * 256 + bxh * 128;

    bf16x8 af[2][4];
#pragma unroll
    for (int nt = 0; nt < 2; ++nt)
#pragma unroll
        for (int is = 0; is < 4; ++is)
            af[nt][is] = *(const bf16x8*)&T[(nloc + nt * 16 + l15) * KJ_STRIDE + is * 32 + 8 * h];

    f32x4 acc[2][8];
#pragma unroll
    for (int nt = 0; nt < 2; ++nt) {
        f32x4 binit;
#pragma unroll
        for (int r = 0; r < 4; ++r)
            binit[r] = bf2f(T[(nloc + nt * 16 + 4 * h + r) * KJ_STRIDE + 128]);   // bias i=128
#pragma unroll
        for (int ct = 0; ct < 8; ++ct) acc[nt][ct] = binit;
    }

#pragma unroll
    for (int is = 0; is < 4; ++is)
#pragma unroll
        for (int ct = 0; ct < 8; ++ct) {
            bf16x8 xf = *(const bf16x8*)&XB[(bxh * 128 + ct * 16 + l15) * XB_STRIDE + is * 32 + 8 * h];
            acc[0][ct] = __builtin_amdgcn_mfma_f32_16x16x32_bf16(af[0][is], xf, acc[0][ct], 0, 0, 0);
            acc[1][ct] = __builtin_amdgcn_mfma_f32_16x16x32_bf16(af[1][is], xf, acc[1][ct], 0, 0, 0);
        }

#pragma unroll
    for (int nt = 0; nt < 2; ++nt)
#pragma unroll
        for (int ct = 0; ct < 8; ++ct) {
            ushort4_t o;
#pragma unroll
            for (int r = 0; r < 4; ++r) o[r] = f2bf(acc[nt][ct][r]);
            *(ushort4_t*)(A2g + (size_t)(bx0 + ct * 16 + l15) * NFLATP + nglob + nt * 16 + 4 * h) = o;
        }
}

// ---------------- stage2: per (b,x) block -> S[y,z] 256x256 (UNCHANGED baseline) ----------------
__global__ __launch_bounds__(512, 4) void stage2_kernel(const unsigned short* __restrict__ ybf,
                                                        const unsigned short* __restrict__ zbf,
                                                        const unsigned short* __restrict__ A2g,
                                                        float* __restrict__ out) {
    const int bx  = blockIdx.x;            // b*256 + x
    const int b   = bx >> 8;
    const int tid = threadIdx.x;
    const int wv = tid >> 6, lane = tid & 63;
    const int l15 = lane & 15, h = lane >> 4;

    __shared__ __align__(16) unsigned short SH[LL * P_STRIDE];   // 67584 B

    {   // pure vector staging: A2 row layout == LDS layout
        const float4* src = (const float4*)(A2g + (size_t)bx * NFLATP);
        float4* dst = (float4*)SH;
        for (int t = tid; t < NFLATP / 8; t += 512) dst[t] = src[t];
    }
    __syncthreads();

    const unsigned short* yb = ybf + b * LL * NI;
    const unsigned short* zb = zbf + b * LL * NI;
    const int y0 = wv * 32;                // wave owns 32 of 256 y in phase A

    // ---- Phase A: P'[k,y] = sum_j A2[k,j]*y[y,j] + A2[k,128] ----
    f32x4 accP[8][2];                      // [k-tile][y-tile]; lane: y=l15(col), k=4h+r(row)
#pragma unroll
    for (int kt = 0; kt < 8; ++kt)
#pragma unroll
        for (int r = 0; r < 4; ++r) {
            float bias = bf2f(SH[(kt * 16 + 4 * h + r) * KJ_STRIDE + 128]);
            accP[kt][0][r] = bias; accP[kt][1][r] = bias;
        }
#pragma unroll
    for (int js = 0; js < 4; ++js) {
        bf16x8 yf[2];
#pragma unroll
        for (int yt = 0; yt < 2; ++yt)
            yf[yt] = *(const bf16x8*)(yb + (y0 + yt * 16 + l15) * NI + js * 32 + 8 * h);
#pragma unroll
        for (int kt = 0; kt < 8; ++kt) {
            bf16x8 af = *(const bf16x8*)&SH[(kt * 16 + l15) * KJ_STRIDE + js * 32 + 8 * h];
            accP[kt][0] = __builtin_amdgcn_mfma_f32_16x16x32_bf16(af, yf[0], accP[kt][0], 0, 0, 0);
            accP[kt][1] = __builtin_amdgcn_mfma_f32_16x16x32_bf16(af, yf[1], accP[kt][1], 0, 0, 0);
        }
    }
    __syncthreads();   // all waves done reading A2 region

    // ---- P' -> LDS [y][P_STRIDE] bf16 ----
#pragma unroll
    for (int kt = 0; kt < 8; ++kt)
#pragma unroll
        for (int yt = 0; yt < 2; ++yt) {
            unsigned lo = (unsigned)f2bf(accP[kt][yt][0]) | ((unsigned)f2bf(accP[kt][yt][1]) << 16);
            unsigned hi = (unsigned)f2bf(accP[kt][yt][2]) | ((unsigned)f2bf(accP[kt][yt][3]) << 16);
            uint2 v; v.x = lo; v.y = hi;
            *(uint2*)&SH[(y0 + yt * 16 + l15) * P_STRIDE + kt * 16 + 4 * h] = v;
        }

    // z fragments: wave owns 64 z-rows, loaded once (overlaps ds_writes above)
    const int zg = wv & 3, yh = wv >> 2;
    const int z0 = zg * 64;
    short4_t zf[4][8];
#pragma unroll
    for (int zt = 0; zt < 4; ++zt)
#pragma unroll
        for (int kt = 0; kt < 8; ++kt)
            zf[zt][kt] = *(const short4_t*)(zb + (z0 + zt * 16 + l15) * NI + kt * 16 + 4 * h);

    __syncthreads();   // P' visible

    // ---- Phase B: S[y,z] = sum_k z[z,k]*P'[k,y]; wave: 64 z x 128 y ----
    float* outb = out + (size_t)bx * (LL * LL);
#pragma unroll 1
    for (int yti = 0; yti < 8; ++yti) {
        const int yy = yh * 128 + yti * 16 + l15;    // this lane's y (col)
        f32x4 acc2[4];
#pragma unroll
        for (int zt = 0; zt < 4; ++zt) { acc2[zt][0] = 0.f; acc2[zt][1] = 0.f; acc2[zt][2] = 0.f; acc2[zt][3] = 0.f; }
#pragma unroll
        for (int kt = 0; kt < 8; ++kt) {
            short4_t pB = *(const short4_t*)&SH[yy * P_STRIDE + kt * 16 + 4 * h];
#pragma unroll
            for (int zt = 0; zt < 4; ++zt)
                acc2[zt] = __builtin_amdgcn_mfma_f32_16x16x16bf16_1k(zf[zt][kt], pB, acc2[zt], 0, 0, 0);
        }
#pragma unroll
        for (int zt = 0; zt < 4; ++zt)
            *(f32x4*)(outb + (size_t)yy * LL + z0 + zt * 16 + 4 * h) = acc2[zt];
    }
}

extern "C" void kernel_launch(void* const* d_in, const int* in_sizes, int n_in,
                              void* d_out, int out_size, void* d_ws, size_t ws_size,
                              hipStream_t stream) {
    const float* x = (const float*)d_in[0];
    const float* y = (const float*)d_in[1];
    const float* z = (const float*)d_in[2];
    const float* W = (const float*)d_in[3];   // [129][128][129][1] = [129][16512]
    float* out = (float*)d_out;

    unsigned short* yzbf = (unsigned short*)d_ws;            // y:65536 + z:65536
    unsigned short* A2g  = yzbf + 131072;                    // 512*17408 (~17.8 MB)

    stage1f_kernel<<<336, 512, 0, stream>>>(W, x, y, z, yzbf, A2g);
    stage2_kernel<<<512, 512, 0, stream>>>(yzbf, yzbf + 65536, A2g, out);
}